// Round 6
// baseline (1914.090 us; speedup 1.0000x reference)
//
#include <hip/hip_runtime.h>
#include <stdint.h>

typedef __attribute__((ext_vector_type(4))) float floatx4;
typedef __bf16 bf16x8 __attribute__((ext_vector_type(8)));
typedef unsigned short ushort_t;

// float -> bf16 round-to-nearest-even (raw bits)
__device__ __forceinline__ ushort_t f2bf(float f) {
  unsigned u = __float_as_uint(f);
  u += 0x7FFFu + ((u >> 16) & 1u);
  return (ushort_t)(u >> 16);
}

// async global->LDS, 16B per lane. LDS dest is wave-uniform base + lane*16.
__device__ __forceinline__ void gl_lds16(const void* g, void* l) {
  __builtin_amdgcn_global_load_lds(
      (__attribute__((address_space(1))) void*)g,
      (__attribute__((address_space(3))) void*)l, 16, 0, 0);
}

// raw barrier WITHOUT waitcnt drain; counted vmcnt keeps loads in flight
// across barriers (T4). asm memory clobber fences compiler code motion.
#define BAR() asm volatile("s_barrier" ::: "memory")
#define VM6() asm volatile("s_waitcnt vmcnt(6)" ::: "memory")
#define LGK0() asm volatile("s_waitcnt lgkmcnt(0)" ::: "memory")

// ---------------- fp32 -> bf16 conversion (vectorized) ----------------
__global__ void cvt_f32_bf16(const float* __restrict__ src,
                             ushort_t* __restrict__ dst, long n) {
  long i = ((long)blockIdx.x * 256 + threadIdx.x) * 4;
  if (i >= n) return;
  float4 v = *(const float4*)(src + i);
  ushort4 o;
  o.x = f2bf(v.x); o.y = f2bf(v.y); o.z = f2bf(v.z); o.w = f2bf(v.w);
  *(ushort4*)(dst + i) = o;
}

// ---------------- bf16 GEMM, C = alpha * A * B^T (+bias) ----------------
// 128x128 tile, BK=64, 256 thr = 2(M)x2(N) waves, per-wave 64x64 output.
// LDS 64 KiB -> TWO independent blocks/CU (the round-5 256-tile used 128 KiB
// = 1 block/CU; all 8 waves lockstep on barriers and the MFMA pipe idled
// ~60% in the collective ds_read/barrier windows). Same 8-phase schedule as
// round-5 (verified on HW): per phase {ds_read subtile | stage ONE half-tile
// (2 gl_lds/wave)} BAR lgkmcnt(0) setprio(1) 8xMFMA setprio(0) [vmcnt(6) at
// P3/P7 only] BAR. Quadrants (0,0),(0,1),(1,1),(1,0); bq0 lives P0->P3,
// bq1 P1->P2. Stage targets (region died >=1 barrier earlier):
//   P0: Ah1(v)->bv    P1: Ah0(u+2)->bu  P2: Bh0(u+2)->bu  P3: Bh1(u+2)->bu
//   P4: Ah1(u+2)->bu  P5: Ah0(v+2)->bv  P6: Bh0(v+2)->bv  P7: Bh1(v+2)->bv
// vmcnt(6)@P3: retires prev-P5..P7 + P0 => tile v fully published pre-P4.
// vmcnt(6)@P7: retires P1..P4 => tile u+2 published pre-next-P0.
// In-flight 6..14 loads, never drained to 0 (T4). Requires nt even (K=2048).
// LDS swizzle (T2): linear gl_lds dest + inverse-swizzled GLOBAL source
// (colblk ^= row&7) + same XOR on ds_read address (rule #21 involution).
// MODE 0: fp32 C[r*ldc+c]  = alpha*acc        (z-strided)
// MODE 3: fp32 C[r*ldc+c]  = acc + bias[c]
// MODE 4: fp32 C[r*ldc+c] += alpha*acc        (z-strided)
// MODE 5: fused QKV routing, QS=strideC elements per slab:
//         c<2048:  C[r*2048+c]                      (Q [b][n][d])
//         c<4096:  C[QS + r*2048 + (c-2048)]        (K [b][n][d])
//         else:    C[2*QS + (r>>11)*4194304 + (c-4096)*2048 + (r&2047)] (V^T)
template <int MODE>
__global__ __launch_bounds__(256, 2) void gemm128(
    const ushort_t* __restrict__ Abase, const ushort_t* __restrict__ Bbase,
    void* __restrict__ Cbase, const float* __restrict__ bias,
    int K, int lda, int ldb, int ldc,
    long strideA, long strideB, long strideC, float alpha) {
  __shared__ alignas(16) ushort_t sAB[2][2][128 * 64];

  const int z = blockIdx.z;
  const ushort_t* A = Abase + (long)z * strideA;
  const ushort_t* B = Bbase + (long)z * strideB;

  // bijective XCD swizzle (m204): contiguous chunk of flat ids per XCD.
  int bx, by;
  {
    const int gx = gridDim.x;
    const int nwg = gx * gridDim.y;
    const int f = blockIdx.x + gx * blockIdx.y;
    const int q = nwg >> 3, r = nwg & 7;
    const int xcd = f & 7, idx = f >> 3;
    const int fs = (xcd < r ? xcd * (q + 1) : r * (q + 1) + (xcd - r) * q) + idx;
    bx = fs % gx;
    by = fs / gx;
  }
  const int row0 = by * 128;  // M
  const int col0 = bx * 128;  // N

  const int tid  = threadIdx.x;
  const int lane = tid & 63;
  const int wave = tid >> 6;  // 0..3
  const int wm   = wave >> 1; // 0..1
  const int wn   = wave & 1;  // 0..1

  const int fr = lane & 15;   // row-in-16 for fragment reads
  const int kq = lane >> 4;   // k-octet 0..3

  // staging lane geometry: within one gl_lds (1 KiB = 8 rows x 128 B),
  // lane l -> row (l>>3), colblk (l&7). Pre-swizzle the GLOBAL colblk.
  const int srow = lane >> 3;                 // row&7 of this lane's slice
  const int scol = ((lane & 7) ^ srow) * 8;   // inverse-swizzled col (elems)

  // ds_read swizzled column offsets (elements), ks = k-sub (0: k0..31, 1: k32..63)
  const int kx0 = ((kq << 3)) ^ ((fr & 7) << 3);
  const int kx1 = ((1 << 5) | (kq << 3)) ^ ((fr & 7) << 3);

  // per-thread global staging bases (chunk row added per call)
  const ushort_t* Ag = A + (long)(row0 + srow) * lda + scol;
  const ushort_t* Bg = B + (long)(col0 + srow) * ldb + scol;

  const floatx4 zero4 = {0.f, 0.f, 0.f, 0.f};
  floatx4 acc[4][4];
#pragma unroll
  for (int a = 0; a < 4; ++a)
#pragma unroll
    for (int b = 0; b < 4; ++b) acc[a][b] = zero4;

  const int nt = K >> 6;  // K-tiles of 64 (must be even)

  // half-tile stagers: 2 gl_lds per wave = 8 KB block-wide per half.
  // half h covers rows {h*32..h*32+31} u {64+h*32..64+h*32+31} (the rows
  // quadrant q==h reads, for both wm/wn). chunk g = c*4+wave, g=0..7:
  // rb = (g>>2)*64 + h*32 + (g&3)*8.
  auto stA = [&](long kk, int buf, int h) {
#pragma unroll
    for (int c = 0; c < 2; ++c) {
      const int g = c * 4 + wave;
      const int rb = (g >> 2) * 64 + h * 32 + (g & 3) * 8;
      gl_lds16(Ag + (long)rb * lda + kk, &sAB[buf][0][rb * 64]);
    }
  };
  auto stB = [&](long kk, int buf, int h) {
#pragma unroll
    for (int c = 0; c < 2; ++c) {
      const int g = c * 4 + wave;
      const int rb = (g >> 2) * 64 + h * 32 + (g & 3) * 8;
      gl_lds16(Bg + (long)rb * ldb + kk, &sAB[buf][1][rb * 64]);
    }
  };

  // prologue: tile0 all 4 halves -> buf0; tile1 {Ah0,Bh0,Bh1} -> buf1.
  // vmcnt(6) retires tile0 (8 loads), leaves tile1's 3 halves in flight.
  stA(0, 0, 0); stA(0, 0, 1); stB(0, 0, 0); stB(0, 0, 1);
  stA(64, 1, 0); stB(64, 1, 0); stB(64, 1, 1);
  VM6();
  BAR();

#define RD_AF(SRC, QM)                                                        \
  _Pragma("unroll") for (int mi = 0; mi < 2; ++mi) {                          \
    const int rowb = (wm * 64 + (QM)*32 + mi * 16 + fr) * 64;                 \
    af[mi][0] = *(const bf16x8*)&(SRC)[rowb + kx0];                           \
    af[mi][1] = *(const bf16x8*)&(SRC)[rowb + kx1];                           \
  }
#define RD_BQ(DST, SRC, QN)                                                   \
  _Pragma("unroll") for (int nj = 0; nj < 2; ++nj) {                          \
    const int rowb = (wn * 64 + (QN)*32 + nj * 16 + fr) * 64;                 \
    DST[nj][0] = *(const bf16x8*)&(SRC)[rowb + kx0];                          \
    DST[nj][1] = *(const bf16x8*)&(SRC)[rowb + kx1];                          \
  }
#define MFMA_Q(QM, QN, BQ)                                                    \
  _Pragma("unroll") for (int mi = 0; mi < 2; ++mi)                            \
  _Pragma("unroll") for (int nj = 0; nj < 2; ++nj)                            \
  _Pragma("unroll") for (int ks = 0; ks < 2; ++ks)                            \
      acc[(QM)*2 + mi][(QN)*2 + nj] = __builtin_amdgcn_mfma_f32_16x16x32_bf16( \
          af[mi][ks], BQ[nj][ks], acc[(QM)*2 + mi][(QN)*2 + nj], 0, 0, 0);
#define PRIO1() __builtin_amdgcn_s_setprio(1)
#define PRIO0() __builtin_amdgcn_s_setprio(0)

  const long kl = (long)(nt - 1) << 6;  // clamp (stale writes land in dead regions)
  const int niter = nt >> 1;
  const ushort_t* sAu = sAB[0][0];
  const ushort_t* sBu = sAB[0][1];
  const ushort_t* sAv = sAB[1][0];
  const ushort_t* sBv = sAB[1][1];

  for (int i = 0; i < niter; ++i) {
    const long kv = (long)(2 * i + 1) << 6;
    long ku2 = (long)(2 * i + 2) << 6; if (ku2 > kl) ku2 = kl;
    long kv2 = (long)(2 * i + 3) << 6; if (kv2 > kl) kv2 = kl;
    bf16x8 af[2][2], bq0[2][2], bq1[2][2];

    // ---- P0: u quadrant (0,0); stage Ah1(v)->bv [died prev P6]
    RD_AF(sAu, 0); RD_BQ(bq0, sBu, 0);
    stA(kv, 1, 1);
    BAR(); LGK0(); PRIO1(); MFMA_Q(0, 0, bq0); PRIO0(); BAR();

    // ---- P1: u quadrant (0,1); stage Ah0(u+2)->bu [died P0]
    RD_BQ(bq1, sBu, 1);
    stA(ku2, 0, 0);
    BAR(); LGK0(); PRIO1(); MFMA_Q(0, 1, bq1); PRIO0(); BAR();

    // ---- P2: u quadrant (1,1); stage Bh0(u+2)->bu [died P0]
    RD_AF(sAu, 1);
    stB(ku2, 0, 0);
    BAR(); LGK0(); PRIO1(); MFMA_Q(1, 1, bq1); PRIO0(); BAR();

    // ---- P3: u quadrant (1,0) (regs only); stage Bh1(u+2)->bu [died P1]
    stB(ku2, 0, 1);
    BAR(); PRIO1(); MFMA_Q(1, 0, bq0); PRIO0();
    VM6();  // retires prev-P5..P7 + P0 => tile v fully published
    BAR();

    // ---- P4: v quadrant (0,0); stage Ah1(u+2)->bu [died P2]
    RD_AF(sAv, 0); RD_BQ(bq0, sBv, 0);
    stA(ku2, 0, 1);
    BAR(); LGK0(); PRIO1(); MFMA_Q(0, 0, bq0); PRIO0(); BAR();

    // ---- P5: v quadrant (0,1); stage Ah0(v+2)->bv [died P4]
    RD_BQ(bq1, sBv, 1);
    stA(kv2, 1, 0);
    BAR(); LGK0(); PRIO1(); MFMA_Q(0, 1, bq1); PRIO0(); BAR();

    // ---- P6: v quadrant (1,1); stage Bh0(v+2)->bv [died P4]
    RD_AF(sAv, 1);
    stB(kv2, 1, 0);
    BAR(); LGK0(); PRIO1(); MFMA_Q(1, 1, bq1); PRIO0(); BAR();

    // ---- P7: v quadrant (1,0); stage Bh1(v+2)->bv [died P5]
    stB(kv2, 1, 1);
    BAR(); PRIO1(); MFMA_Q(1, 0, bq0); PRIO0();
    VM6();  // retires P1..P4 => tile u+2 fully published
    BAR();
  }
#undef RD_AF
#undef RD_BQ
#undef MFMA_Q

  // C/D layout: col = lane&15, row = (lane>>4)*4 + reg   [verified m89/m91]
  const int ccol  = lane & 15;
  const int crow4 = (lane >> 4) * 4;

  if (MODE == 0 || MODE == 3 || MODE == 4) {
    float* C = (float*)Cbase + (long)z * strideC;
#pragma unroll
    for (int a = 0; a < 4; ++a) {
      const int rbase = row0 + wm * 64 + (a >> 1) * 32 + (a & 1) * 16 + crow4;
#pragma unroll
      for (int b = 0; b < 4; ++b) {
        const int c = col0 + wn * 64 + (b >> 1) * 32 + (b & 1) * 16 + ccol;
        const float bb = (MODE == 3) ? bias[c] : 0.f;
#pragma unroll
        for (int r = 0; r < 4; ++r) {
          const long idx = (long)(rbase + r) * ldc + c;
          float v;
          if (MODE == 3)      v = acc[a][b][r] + bb;
          else if (MODE == 4) v = C[idx] + alpha * acc[a][b][r];
          else                v = alpha * acc[a][b][r];
          C[idx] = v;
        }
      }
    }
  } else {  // MODE 5
    ushort_t* C = (ushort_t*)Cbase;
    const long QS = strideC;
#pragma unroll
    for (int a = 0; a < 4; ++a) {
      const int rbase = row0 + wm * 64 + (a >> 1) * 32 + (a & 1) * 16 + crow4;
#pragma unroll
      for (int b = 0; b < 4; ++b) {
        const int c = col0 + wn * 64 + (b >> 1) * 32 + (b & 1) * 16 + ccol;
#pragma unroll
        for (int r = 0; r < 4; ++r) {
          const int rr = rbase + r;
          const ushort_t v = f2bf(acc[a][b][r]);
          if (c < 2048)
            C[(long)rr * 2048 + c] = v;
          else if (c < 4096)
            C[QS + (long)rr * 2048 + (c - 2048)] = v;
          else
            C[2 * QS + (long)(rr >> 11) * 4194304 + (long)(c - 4096) * 2048 +
              (rr & 2047)] = v;
        }
      }
    }
  }
}

// ---------------- online column softmax (over query axis n) ----------------
__global__ void softmax_cols(const float* __restrict__ Sbase,
                             ushort_t* __restrict__ wbase) {
  __shared__ float rmx[8][32], rsum[8][32];
  const long zoff = (long)blockIdx.y * 4194304;
  const int tx = threadIdx.x & 31;
  const int ty = threadIdx.x >> 5;
  const int m = blockIdx.x * 32 + tx;
  const float* Sm = Sbase + zoff + m;
  const int n0 = ty * 256;

  float mx = -3.0e38f, sum = 0.f;
#pragma unroll 4
  for (int n = n0; n < n0 + 256; ++n) {
    const float v = Sm[(long)n * 2048];
    if (v > mx) {
      sum = sum * __expf(mx - v) + 1.f;
      mx = v;
    } else {
      sum += __expf(v - mx);
    }
  }
  rmx[ty][tx] = mx;
  rsum[ty][tx] = sum;
  __syncthreads();
  float gm = rmx[0][tx];
#pragma unroll
  for (int s = 1; s < 8; ++s) gm = fmaxf(gm, rmx[s][tx]);
  float gs = 0.f;
#pragma unroll
  for (int s = 0; s < 8; ++s) gs += rsum[s][tx] * __expf(rmx[s][tx] - gm);
  const float inv = 1.f / gs;

  ushort_t* wm_ = wbase + zoff + m;
#pragma unroll 4
  for (int n = n0; n < n0 + 256; ++n)
    wm_[(long)n * 2048] = f2bf(__expf(Sm[(long)n * 2048] - gm) * inv);
}

extern "C" void kernel_launch(void* const* d_in, const int* in_sizes, int n_in,
                              void* d_out, int out_size, void* d_ws,
                              size_t ws_size, hipStream_t stream) {
  const float* x   = (const float*)d_in[0];
  const float* Wq  = (const float*)d_in[1];
  const float* Wk  = (const float*)d_in[2];
  const float* Wv  = (const float*)d_in[3];
  const float* fcw = (const float*)d_in[4];
  const float* fcb = (const float*)d_in[5];
  float* out = (float*)d_out;

  char* ws = (char*)d_ws;
  size_t off = 0;
  auto alloc = [&](size_t bytes) {
    char* p = ws + off;
    off += (bytes + 255) & ~(size_t)255;
    return p;
  };
  const long SL = 4194304L;  // 2048*2048 elements
  const dim3 blk(256);
  const float scale = 0.022097086912079608f;  // 1/sqrt(2048)

  // persistent
  ushort_t* xb   = (ushort_t*)alloc(33554432);  // x bf16 [8192][2048]
  ushort_t* fcwb = (ushort_t*)alloc(8388608);   // fc_w bf16
  float* mean32 = out;                          // fp32 head-sum accumulator in d_out
  char* loop0 = ws + off;

  cvt_f32_bf16<<<16384, blk, 0, stream>>>(x, xb, 16777216L);
  cvt_f32_bf16<<<4096, blk, 0, stream>>>(fcw, fcwb, 4194304L);

  // Layout A (batched over all b) needs 234,881,024 bytes total.
  const bool big = ws_size >= 234881024ULL;

  if (big) {
    ushort_t* Wcat = (ushort_t*)alloc(25165824);   // [6144][2048] bf16
    ushort_t* Qh   = (ushort_t*)alloc(33554432);   // [4][2048][2048]
    ushort_t* Kh   = (ushort_t*)alloc(33554432);   // contiguous after Qh
    ushort_t* Vth  = (ushort_t*)alloc(33554432);   // [4][2048 d][2048 m]
    float*    S    = (float*)alloc(67108864);      // [4][2048][2048] fp32
    ushort_t* wc   = Qh;                           // overlay (Q dead post-scores)
    (void)Kh; (void)Vth;

    for (int h = 0; h < 3; ++h) {
      cvt_f32_bf16<<<4096, blk, 0, stream>>>(Wq + h * SL, Wcat, SL);
      cvt_f32_bf16<<<4096, blk, 0, stream>>>(Wk + h * SL, Wcat + SL, SL);
      cvt_f32_bf16<<<4096, blk, 0, stream>>>(Wv + h * SL, Wcat + 2 * SL, SL);

      // fused QKV projection: M=8192, N=6144; QS slab = 16777216 elements
      gemm128<5><<<dim3(48, 64), blk, 0, stream>>>(
          xb, Wcat, Qh, nullptr, 2048, 2048, 2048, 2048,
          0L, 0L, 16777216L, 1.0f);
      // scores, batched z=b
      gemm128<0><<<dim3(16, 16, 4), blk, 0, stream>>>(
          Qh, Qh + 16777216L, S, nullptr, 2048, 2048, 2048, 2048,
          SL, SL, SL, scale);
      softmax_cols<<<dim3(64, 4), blk, 0, stream>>>(S, wc);
      // mean32[b] (+)= (1/3) * wc[b] @ Vth[b]^T
      if (h == 0)
        gemm128<0><<<dim3(16, 16, 4), blk, 0, stream>>>(
            wc, Qh + 33554432L, mean32, nullptr, 2048, 2048, 2048, 2048,
            SL, SL, SL, 1.0f / 3.0f);
      else
        gemm128<4><<<dim3(16, 16, 4), blk, 0, stream>>>(
            wc, Qh + 33554432L, mean32, nullptr, 2048, 2048, 2048, 2048,
            SL, SL, SL, 1.0f / 3.0f);
    }
  } else {
    // compact: exact round-3 footprint (109,051,904 bytes; proven safe)
    ushort_t* Wqh  = (ushort_t*)alloc(8388608);  // [2048][2048] -+
    ushort_t* Wkh  = (ushort_t*)alloc(8388608);  //               | contiguous
    ushort_t* Wvh  = (ushort_t*)alloc(8388608);  //              -+ = [6144][2048]
    ushort_t* Qhb  = (ushort_t*)alloc(8388608);  // [2048][2048] -+
    ushort_t* Khb  = (ushort_t*)alloc(8388608);  //               | contiguous
    ushort_t* Vthb = (ushort_t*)alloc(8388608);  //              -+
    float*    S    = (float*)alloc(16777216);    // [2048][2048] fp32
    ushort_t* wchb = Qhb;                        // overlay
    (void)Wkh; (void)Wvh; (void)Khb; (void)Vthb;

    for (int h = 0; h < 3; ++h) {
      cvt_f32_bf16<<<4096, blk, 0, stream>>>(Wq + h * SL, Wqh, SL);
      cvt_f32_bf16<<<4096, blk, 0, stream>>>(Wk + h * SL, Wqh + SL, SL);
      cvt_f32_bf16<<<4096, blk, 0, stream>>>(Wv + h * SL, Wqh + 2 * SL, SL);

      for (int b = 0; b < 4; ++b) {
        const ushort_t* xbb = xb + b * SL;
        // fused QKV projection: M=2048, N=6144; QS slab = 4194304 elements
        gemm128<5><<<dim3(48, 16), blk, 0, stream>>>(
            xbb, Wqh, Qhb, nullptr, 2048, 2048, 2048, 2048,
            0L, 0L, 4194304L, 1.0f);
        gemm128<0><<<dim3(16, 16), blk, 0, stream>>>(
            Qhb, Qhb + SL, S, nullptr, 2048, 2048, 2048, 2048,
            0L, 0L, 0L, scale);
        softmax_cols<<<dim3(64, 1), blk, 0, stream>>>(S, wchb);
        if (h == 0)
          gemm128<0><<<dim3(16, 16), blk, 0, stream>>>(
              wchb, Qhb + 2 * SL, mean32 + b * SL, nullptr, 2048,
              2048, 2048, 2048, 0L, 0L, 0L, 1.0f / 3.0f);
        else
          gemm128<4><<<dim3(16, 16), blk, 0, stream>>>(
              wchb, Qhb + 2 * SL, mean32 + b * SL, nullptr, 2048,
              2048, 2048, 2048, 0L, 0L, 0L, 1.0f / 3.0f);
      }
    }
  }

  // mean (in d_out) -> bf16 overlay in loop region, then out = mean@fc_w^T + fc_b
  ushort_t* meanb = (ushort_t*)loop0;
  cvt_f32_bf16<<<16384, blk, 0, stream>>>(mean32, meanb, 16777216L);
  gemm128<3><<<dim3(16, 64), blk, 0, stream>>>(
      meanb, fcwb, out, fcb, 2048, 2048, 2048, 2048,
      0L, 0L, 0L, 1.0f);
}

// Round 7
// 1775.154 us; speedup vs baseline: 1.0783x; 1.0783x over previous
//
#include <hip/hip_runtime.h>
#include <stdint.h>

typedef __attribute__((ext_vector_type(4))) float floatx4;
typedef __bf16 bf16x8 __attribute__((ext_vector_type(8)));
typedef unsigned short ushort_t;

// float -> bf16 round-to-nearest-even (raw bits)
__device__ __forceinline__ ushort_t f2bf(float f) {
  unsigned u = __float_as_uint(f);
  u += 0x7FFFu + ((u >> 16) & 1u);
  return (ushort_t)(u >> 16);
}

// async global->LDS, 16B per lane. LDS dest is wave-uniform base + lane*16.
__device__ __forceinline__ void gl_lds16(const void* g, void* l) {
  __builtin_amdgcn_global_load_lds(
      (__attribute__((address_space(1))) void*)g,
      (__attribute__((address_space(3))) void*)l, 16, 0, 0);
}

// raw barrier WITHOUT waitcnt drain; counted vmcnt keeps loads in flight
// across barriers (T4). asm memory clobber fences compiler code motion.
#define BAR() asm volatile("s_barrier" ::: "memory")
#define VM6() asm volatile("s_waitcnt vmcnt(6)" ::: "memory")

// ---------------- fp32 -> bf16 conversion (vectorized) ----------------
__global__ void cvt_f32_bf16(const float* __restrict__ src,
                             ushort_t* __restrict__ dst, long n) {
  long i = ((long)blockIdx.x * 256 + threadIdx.x) * 4;
  if (i >= n) return;
  float4 v = *(const float4*)(src + i);
  ushort4 o;
  o.x = f2bf(v.x); o.y = f2bf(v.y); o.z = f2bf(v.z); o.w = f2bf(v.w);
  *(ushort4*)(dst + i) = o;
}

// ---------------- bf16 GEMM, C = alpha * A * B^T (+bias) ----------------
// 256x256 tile, BK=64, 512 thr = 2(M)x4(N) waves, per-wave 128x64 output.
// Round-5 8-phase counted-vmcnt schedule MINUS the mid-phase barrier+lgkm0:
// round-5 measured 856 TF / MfmaUtil 37% with the MFMA pipe idle during the
// collective read windows (2 BAR/phase = full lockstep; blanket lgkmcnt(0)
// serialized all reads before the first MFMA). Dependency re-derivation:
// the pre-MFMA barrier is NOT load-bearing -- every stage targets a region
// whose ds_reads retired >=1 PHASE-END barrier earlier (reads are consumed
// by the same phase's MFMAs, so compiler dataflow waits retire them before
// the wave reaches its phase-end barrier), and publishing is VM6+BAR.
// Per phase now: {ds_read subtile | stage ONE half (2 gl_lds/thr)} setprio(1)
// 16xMFMA setprio(0) [vmcnt(6) at P3/P7] BAR. Compiler fine-grained lgkmcnt
// interleaves reads with MFMAs (m97); 2 waves/SIMD slip within a phase.
//   P0: Ah1(v)->bv    P1: Ah0(u+2)->bu  P2: Bh0(u+2)->bu  P3: Bh1(u+2)->bu
//   P4: Ah1(u+2)->bu  P5: Ah0(v+2)->bv  P6: Bh0(v+2)->bv  P7: Bh1(v+2)->bv
// vmcnt(6)@P3: retires prev-P5..P7 + P0 => tile v fully published pre-P4.
// vmcnt(6)@P7: retires P1..P4 => tile u+2 published pre-next-P0.
// In-flight 6..14 loads, never drained to 0 (T4). Requires nt even (K=2048).
// LDS swizzle (T2): linear gl_lds dest + inverse-swizzled GLOBAL source
// (colblk ^= row&7) + same XOR on ds_read address (rule #21 involution).
// MODE 0: fp32 C[r*ldc+c]  = alpha*acc        (z-strided)
// MODE 3: fp32 C[r*ldc+c]  = acc + bias[c]
// MODE 4: fp32 C[r*ldc+c] += alpha*acc        (z-strided)
// MODE 5: fused QKV routing, QS=strideC elements per slab:
//         c<2048:  C[r*2048+c]                      (Q [b][n][d])
//         c<4096:  C[QS + r*2048 + (c-2048)]        (K [b][n][d])
//         else:    C[2*QS + (r>>11)*4194304 + (c-4096)*2048 + (r&2047)] (V^T)
template <int MODE>
__global__ __launch_bounds__(512, 2) void gemm256(
    const ushort_t* __restrict__ Abase, const ushort_t* __restrict__ Bbase,
    void* __restrict__ Cbase, const float* __restrict__ bias,
    int K, int lda, int ldb, int ldc,
    long strideA, long strideB, long strideC, float alpha) {
  __shared__ alignas(16) ushort_t sAB[2][2][256 * 64];

  const int z = blockIdx.z;
  const ushort_t* A = Abase + (long)z * strideA;
  const ushort_t* B = Bbase + (long)z * strideB;

  // bijective XCD swizzle (m204): contiguous chunk of flat ids per XCD.
  int bx, by;
  {
    const int gx = gridDim.x;
    const int nwg = gx * gridDim.y;
    const int f = blockIdx.x + gx * blockIdx.y;
    const int q = nwg >> 3, r = nwg & 7;
    const int xcd = f & 7, idx = f >> 3;
    const int fs = (xcd < r ? xcd * (q + 1) : r * (q + 1) + (xcd - r) * q) + idx;
    bx = fs % gx;
    by = fs / gx;
  }
  const int row0 = by * 256;  // M
  const int col0 = bx * 256;  // N

  const int tid  = threadIdx.x;
  const int lane = tid & 63;
  const int wave = tid >> 6;  // 0..7
  const int wm   = wave >> 2; // 0..1
  const int wn   = wave & 3;  // 0..3

  const int fr = lane & 15;   // row-in-16 for fragment reads
  const int kq = lane >> 4;   // k-octet 0..3

  // staging lane geometry: within one gl_lds (1 KiB = 8 rows x 128 B),
  // lane l -> row (l>>3), colblk (l&7). Pre-swizzle the GLOBAL colblk.
  const int srow = lane >> 3;                 // row&7 of this lane's slice
  const int scol = ((lane & 7) ^ srow) * 8;   // inverse-swizzled col (elems)

  // ds_read swizzled column offsets (elements), ks = k-sub (0: k0..31, 1: k32..63)
  const int kx0 = ((kq << 3)) ^ ((fr & 7) << 3);
  const int kx1 = ((1 << 5) | (kq << 3)) ^ ((fr & 7) << 3);

  // per-thread global staging bases (chunk row added per call)
  const ushort_t* Ag = A + (long)(row0 + srow) * lda + scol;
  const ushort_t* Bg = B + (long)(col0 + srow) * ldb + scol;

  const floatx4 zero4 = {0.f, 0.f, 0.f, 0.f};
  floatx4 acc[8][4];
#pragma unroll
  for (int a = 0; a < 8; ++a)
#pragma unroll
    for (int b = 0; b < 4; ++b) acc[a][b] = zero4;

  const int nt = K >> 6;  // K-tiles of 64 (must be even)

  // half-tile stagers: 2 gl_lds per thread = 16 KB block-wide.
  // A half h: rows {h*64..+63} and {128+h*64..+63}  (af reads for qm=h)
  auto stA = [&](long kk, int buf, int h) {
#pragma unroll
    for (int c = 0; c < 2; ++c) {
      const int rb = c * 128 + h * 64 + wave * 8;
      gl_lds16(Ag + (long)rb * lda + kk, &sAB[buf][0][rb * 64]);
    }
  };
  // B half h: rows with bit5==h, i.e. (g>>2)*64 + h*32 + (g&3)*8, g=c*8+wave
  auto stB = [&](long kk, int buf, int h) {
#pragma unroll
    for (int c = 0; c < 2; ++c) {
      const int g = c * 8 + wave;
      const int rb = (g >> 2) * 64 + h * 32 + (g & 3) * 8;
      gl_lds16(Bg + (long)rb * ldb + kk, &sAB[buf][1][rb * 64]);
    }
  };

  // prologue: tile0 all 4 halves -> buf0; tile1 {Ah0,Bh0,Bh1} -> buf1.
  // vmcnt(6) retires tile0 (8 loads), leaves tile1's 3 halves in flight.
  stA(0, 0, 0); stA(0, 0, 1); stB(0, 0, 0); stB(0, 0, 1);
  stA(64, 1, 0); stB(64, 1, 0); stB(64, 1, 1);
  VM6();
  BAR();

#define RD_AF(SRC, QM)                                                        \
  _Pragma("unroll") for (int mi = 0; mi < 4; ++mi) {                          \
    const int rowb = (wm * 128 + (QM)*64 + mi * 16 + fr) * 64;                \
    af[mi][0] = *(const bf16x8*)&(SRC)[rowb + kx0];                           \
    af[mi][1] = *(const bf16x8*)&(SRC)[rowb + kx1];                           \
  }
#define RD_BQ(DST, SRC, QN)                                                   \
  _Pragma("unroll") for (int nj = 0; nj < 2; ++nj) {                          \
    const int rowb = (wn * 64 + (QN)*32 + nj * 16 + fr) * 64;                 \
    DST[nj][0] = *(const bf16x8*)&(SRC)[rowb + kx0];                          \
    DST[nj][1] = *(const bf16x8*)&(SRC)[rowb + kx1];                          \
  }
#define MFMA_Q(QM, QN, BQ)                                                    \
  _Pragma("unroll") for (int mi = 0; mi < 4; ++mi)                            \
  _Pragma("unroll") for (int nj = 0; nj < 2; ++nj)                            \
  _Pragma("unroll") for (int ks = 0; ks < 2; ++ks)                            \
      acc[(QM)*4 + mi][(QN)*2 + nj] = __builtin_amdgcn_mfma_f32_16x16x32_bf16( \
          af[mi][ks], BQ[nj][ks], acc[(QM)*4 + mi][(QN)*2 + nj], 0, 0, 0);
#define PRIO1() __builtin_amdgcn_s_setprio(1)
#define PRIO0() __builtin_amdgcn_s_setprio(0)

  const long kl = (long)(nt - 1) << 6;  // clamp (stale writes land in dead regions)
  const int niter = nt >> 1;
  const ushort_t* sAu = sAB[0][0];
  const ushort_t* sBu = sAB[0][1];
  const ushort_t* sAv = sAB[1][0];
  const ushort_t* sBv = sAB[1][1];

  for (int i = 0; i < niter; ++i) {
    const long kv = (long)(2 * i + 1) << 6;
    long ku2 = (long)(2 * i + 2) << 6; if (ku2 > kl) ku2 = kl;
    long kv2 = (long)(2 * i + 3) << 6; if (kv2 > kl) kv2 = kl;
    bf16x8 af[4][2], bq0[2][2], bq1[2][2];

    // ---- P0: u quadrant (0,0); stage Ah1(v)->bv [died prev P6]
    RD_AF(sAu, 0); RD_BQ(bq0, sBu, 0);
    stA(kv, 1, 1);
    PRIO1(); MFMA_Q(0, 0, bq0); PRIO0(); BAR();

    // ---- P1: u quadrant (0,1); stage Ah0(u+2)->bu [died P0]
    RD_BQ(bq1, sBu, 1);
    stA(ku2, 0, 0);
    PRIO1(); MFMA_Q(0, 1, bq1); PRIO0(); BAR();

    // ---- P2: u quadrant (1,1); stage Bh0(u+2)->bu [died P0]
    RD_AF(sAu, 1);
    stB(ku2, 0, 0);
    PRIO1(); MFMA_Q(1, 1, bq1); PRIO0(); BAR();

    // ---- P3: u quadrant (1,0) (regs only); stage Bh1(u+2)->bu [died P1]
    stB(ku2, 0, 1);
    PRIO1(); MFMA_Q(1, 0, bq0); PRIO0();
    VM6();  // retires prev-P5..P7 + P0 => tile v fully published
    BAR();

    // ---- P4: v quadrant (0,0); stage Ah1(u+2)->bu [died P2]
    RD_AF(sAv, 0); RD_BQ(bq0, sBv, 0);
    stA(ku2, 0, 1);
    PRIO1(); MFMA_Q(0, 0, bq0); PRIO0(); BAR();

    // ---- P5: v quadrant (0,1); stage Ah0(v+2)->bv [died P4]
    RD_BQ(bq1, sBv, 1);
    stA(kv2, 1, 0);
    PRIO1(); MFMA_Q(0, 1, bq1); PRIO0(); BAR();

    // ---- P6: v quadrant (1,1); stage Bh0(v+2)->bv [died P4]
    RD_AF(sAv, 1);
    stB(kv2, 1, 0);
    PRIO1(); MFMA_Q(1, 1, bq1); PRIO0(); BAR();

    // ---- P7: v quadrant (1,0); stage Bh1(v+2)->bv [died P5]
    stB(kv2, 1, 1);
    PRIO1(); MFMA_Q(1, 0, bq0); PRIO0();
    VM6();  // retires P1..P4 => tile u+2 fully published
    BAR();
  }
#undef RD_AF
#undef RD_BQ
#undef MFMA_Q

  // C/D layout: col = lane&15, row = (lane>>4)*4 + reg   [verified m89/m91]
  const int ccol  = lane & 15;
  const int crow4 = (lane >> 4) * 4;

  if (MODE == 0 || MODE == 3 || MODE == 4) {
    float* C = (float*)Cbase + (long)z * strideC;
#pragma unroll
    for (int a = 0; a < 8; ++a) {
      const int rbase = row0 + wm * 128 + (a >> 2) * 64 + (a & 3) * 16 + crow4;
#pragma unroll
      for (int b = 0; b < 4; ++b) {
        const int c = col0 + wn * 64 + (b >> 1) * 32 + (b & 1) * 16 + ccol;
        const float bb = (MODE == 3) ? bias[c] : 0.f;
#pragma unroll
        for (int r = 0; r < 4; ++r) {
          const long idx = (long)(rbase + r) * ldc + c;
          float v;
          if (MODE == 3)      v = acc[a][b][r] + bb;
          else if (MODE == 4) v = C[idx] + alpha * acc[a][b][r];
          else                v = alpha * acc[a][b][r];
          C[idx] = v;
        }
      }
    }
  } else {  // MODE 5
    ushort_t* C = (ushort_t*)Cbase;
    const long QS = strideC;
#pragma unroll
    for (int a = 0; a < 8; ++a) {
      const int rbase = row0 + wm * 128 + (a >> 2) * 64 + (a & 3) * 16 + crow4;
#pragma unroll
      for (int b = 0; b < 4; ++b) {
        const int c = col0 + wn * 64 + (b >> 1) * 32 + (b & 1) * 16 + ccol;
#pragma unroll
        for (int r = 0; r < 4; ++r) {
          const int rr = rbase + r;
          const ushort_t v = f2bf(acc[a][b][r]);
          if (c < 2048)
            C[(long)rr * 2048 + c] = v;
          else if (c < 4096)
            C[QS + (long)rr * 2048 + (c - 2048)] = v;
          else
            C[2 * QS + (long)(rr >> 11) * 4194304 + (long)(c - 4096) * 2048 +
              (rr & 2047)] = v;
        }
      }
    }
  }
}

// ---------------- online column softmax (over query axis n) ----------------
__global__ void softmax_cols(const float* __restrict__ Sbase,
                             ushort_t* __restrict__ wbase) {
  __shared__ float rmx[8][32], rsum[8][32];
  const long zoff = (long)blockIdx.y * 4194304;
  const int tx = threadIdx.x & 31;
  const int ty = threadIdx.x >> 5;
  const int m = blockIdx.x * 32 + tx;
  const float* Sm = Sbase + zoff + m;
  const int n0 = ty * 256;

  float mx = -3.0e38f, sum = 0.f;
#pragma unroll 4
  for (int n = n0; n < n0 + 256; ++n) {
    const float v = Sm[(long)n * 2048];
    if (v > mx) {
      sum = sum * __expf(mx - v) + 1.f;
      mx = v;
    } else {
      sum += __expf(v - mx);
    }
  }
  rmx[ty][tx] = mx;
  rsum[ty][tx] = sum;
  __syncthreads();
  float gm = rmx[0][tx];
#pragma unroll
  for (int s = 1; s < 8; ++s) gm = fmaxf(gm, rmx[s][tx]);
  float gs = 0.f;
#pragma unroll
  for (int s = 0; s < 8; ++s) gs += rsum[s][tx] * __expf(rmx[s][tx] - gm);
  const float inv = 1.f / gs;

  ushort_t* wm_ = wbase + zoff + m;
#pragma unroll 4
  for (int n = n0; n < n0 + 256; ++n)
    wm_[(long)n * 2048] = f2bf(__expf(Sm[(long)n * 2048] - gm) * inv);
}

extern "C" void kernel_launch(void* const* d_in, const int* in_sizes, int n_in,
                              void* d_out, int out_size, void* d_ws,
                              size_t ws_size, hipStream_t stream) {
  const float* x   = (const float*)d_in[0];
  const float* Wq  = (const float*)d_in[1];
  const float* Wk  = (const float*)d_in[2];
  const float* Wv  = (const float*)d_in[3];
  const float* fcw = (const float*)d_in[4];
  const float* fcb = (const float*)d_in[5];
  float* out = (float*)d_out;

  char* ws = (char*)d_ws;
  size_t off = 0;
  auto alloc = [&](size_t bytes) {
    char* p = ws + off;
    off += (bytes + 255) & ~(size_t)255;
    return p;
  };
  const long SL = 4194304L;  // 2048*2048 elements
  const dim3 blk(256);
  const dim3 blk512(512);
  const float scale = 0.022097086912079608f;  // 1/sqrt(2048)

  // persistent
  ushort_t* xb   = (ushort_t*)alloc(33554432);  // x bf16 [8192][2048]
  ushort_t* fcwb = (ushort_t*)alloc(8388608);   // fc_w bf16
  float* mean32 = out;                          // fp32 head-sum accumulator in d_out
  char* loop0 = ws + off;

  cvt_f32_bf16<<<16384, blk, 0, stream>>>(x, xb, 16777216L);
  cvt_f32_bf16<<<4096, blk, 0, stream>>>(fcw, fcwb, 4194304L);

  // Layout A (batched over all b) needs 234,881,024 bytes total.
  const bool big = ws_size >= 234881024ULL;

  if (big) {
    ushort_t* Wcat = (ushort_t*)alloc(25165824);   // [6144][2048] bf16
    ushort_t* Qh   = (ushort_t*)alloc(33554432);   // [4][2048][2048]
    ushort_t* Kh   = (ushort_t*)alloc(33554432);   // contiguous after Qh
    ushort_t* Vth  = (ushort_t*)alloc(33554432);   // [4][2048 d][2048 m]
    float*    S    = (float*)alloc(67108864);      // [4][2048][2048] fp32
    ushort_t* wc   = Qh;                           // overlay (Q dead post-scores)
    (void)Kh; (void)Vth;

    for (int h = 0; h < 3; ++h) {
      cvt_f32_bf16<<<4096, blk, 0, stream>>>(Wq + h * SL, Wcat, SL);
      cvt_f32_bf16<<<4096, blk, 0, stream>>>(Wk + h * SL, Wcat + SL, SL);
      cvt_f32_bf16<<<4096, blk, 0, stream>>>(Wv + h * SL, Wcat + 2 * SL, SL);

      // fused QKV projection: M=8192, N=6144; QS slab = 16777216 elements
      gemm256<5><<<dim3(24, 32), blk512, 0, stream>>>(
          xb, Wcat, Qh, nullptr, 2048, 2048, 2048, 2048,
          0L, 0L, 16777216L, 1.0f);
      // scores, batched z=b
      gemm256<0><<<dim3(8, 8, 4), blk512, 0, stream>>>(
          Qh, Qh + 16777216L, S, nullptr, 2048, 2048, 2048, 2048,
          SL, SL, SL, scale);
      softmax_cols<<<dim3(64, 4), blk, 0, stream>>>(S, wc);
      // mean32[b] (+)= (1/3) * wc[b] @ Vth[b]^T
      if (h == 0)
        gemm256<0><<<dim3(8, 8, 4), blk512, 0, stream>>>(
            wc, Qh + 33554432L, mean32, nullptr, 2048, 2048, 2048, 2048,
            SL, SL, SL, 1.0f / 3.0f);
      else
        gemm256<4><<<dim3(8, 8, 4), blk512, 0, stream>>>(
            wc, Qh + 33554432L, mean32, nullptr, 2048, 2048, 2048, 2048,
            SL, SL, SL, 1.0f / 3.0f);
    }
  } else {
    // compact: exact round-3 footprint (109,051,904 bytes; proven safe)
    ushort_t* Wqh  = (ushort_t*)alloc(8388608);  // [2048][2048] -+
    ushort_t* Wkh  = (ushort_t*)alloc(8388608);  //               | contiguous
    ushort_t* Wvh  = (ushort_t*)alloc(8388608);  //              -+ = [6144][2048]
    ushort_t* Qhb  = (ushort_t*)alloc(8388608);  // [2048][2048] -+
    ushort_t* Khb  = (ushort_t*)alloc(8388608);  //               | contiguous
    ushort_t* Vthb = (ushort_t*)alloc(8388608);  //              -+
    float*    S    = (float*)alloc(16777216);    // [2048][2048] fp32
    ushort_t* wchb = Qhb;                        // overlay
    (void)Wkh; (void)Wvh; (void)Khb; (void)Vthb;

    for (int h = 0; h < 3; ++h) {
      cvt_f32_bf16<<<4096, blk, 0, stream>>>(Wq + h * SL, Wqh, SL);
      cvt_f32_bf16<<<4096, blk, 0, stream>>>(Wk + h * SL, Wqh + SL, SL);
      cvt_f32_bf16<<<4096, blk, 0, stream>>>(Wv + h * SL, Wqh + 2 * SL, SL);

      for (int b = 0; b < 4; ++b) {
        const ushort_t* xbb = xb + b * SL;
        // fused QKV projection: M=2048, N=6144; QS slab = 4194304 elements
        gemm256<5><<<dim3(24, 8), blk512, 0, stream>>>(
            xbb, Wqh, Qhb, nullptr, 2048, 2048, 2048, 2048,
            0L, 0L, 4194304L, 1.0f);
        gemm256<0><<<dim3(8, 8), blk512, 0, stream>>>(
            Qhb, Qhb + SL, S, nullptr, 2048, 2048, 2048, 2048,
            0L, 0L, 0L, scale);
        softmax_cols<<<dim3(64, 1), blk, 0, stream>>>(S, wchb);
        if (h == 0)
          gemm256<0><<<dim3(8, 8), blk512, 0, stream>>>(
              wchb, Qhb + 2 * SL, mean32 + b * SL, nullptr, 2048,
              2048, 2048, 2048, 0L, 0L, 0L, 1.0f / 3.0f);
        else
          gemm256<4><<<dim3(8, 8), blk512, 0, stream>>>(
              wchb, Qhb + 2 * SL, mean32 + b * SL, nullptr, 2048,
              2048, 2048, 2048, 0L, 0L, 0L, 1.0f / 3.0f);
      }
    }
  }

  // mean (in d_out) -> bf16 overlay in loop region, then out = mean@fc_w^T + fc_b
  ushort_t* meanb = (ushort_t*)loop0;
  cvt_f32_bf16<<<16384, blk, 0, stream>>>(mean32, meanb, 16777216L);
  gemm256<3><<<dim3(8, 32), blk512, 0, stream>>>(
      meanb, fcwb, out, fcb, 2048, 2048, 2048, 2048,
      0L, 0L, 0L, 1.0f);
}

// Round 8
// 1671.191 us; speedup vs baseline: 1.1453x; 1.0622x over previous
//
#include <hip/hip_runtime.h>
#include <stdint.h>

typedef __attribute__((ext_vector_type(4))) float floatx4;
typedef __bf16 bf16x8 __attribute__((ext_vector_type(8)));
typedef unsigned short ushort_t;

// float -> bf16 round-to-nearest-even (raw bits)
__device__ __forceinline__ ushort_t f2bf(float f) {
  unsigned u = __float_as_uint(f);
  u += 0x7FFFu + ((u >> 16) & 1u);
  return (ushort_t)(u >> 16);
}
__device__ __forceinline__ float bf2f(ushort_t h) {
  return __uint_as_float((unsigned)h << 16);
}

// async global->LDS, 16B per lane. LDS dest is wave-uniform base + lane*16.
__device__ __forceinline__ void gl_lds16(const void* g, void* l) {
  __builtin_amdgcn_global_load_lds(
      (__attribute__((address_space(1))) void*)g,
      (__attribute__((address_space(3))) void*)l, 16, 0, 0);
}

// raw barrier WITHOUT waitcnt drain; counted vmcnt keeps loads in flight
// across barriers (T4). asm memory clobber fences compiler code motion.
#define BAR() asm volatile("s_barrier" ::: "memory")
#define VM6() asm volatile("s_waitcnt vmcnt(6)" ::: "memory")

// ---------------- fp32 -> bf16 conversion (vectorized) ----------------
__global__ void cvt_f32_bf16(const float* __restrict__ src,
                             ushort_t* __restrict__ dst, long n) {
  long i = ((long)blockIdx.x * 256 + threadIdx.x) * 4;
  if (i >= n) return;
  float4 v = *(const float4*)(src + i);
  ushort4 o;
  o.x = f2bf(v.x); o.y = f2bf(v.y); o.z = f2bf(v.z); o.w = f2bf(v.w);
  *(ushort4*)(dst + i) = o;
}

// ---------------- bf16 GEMM, C = alpha * A * B^T (+bias) ----------------
// 256x256 tile, BK=64, 512 thr = 2(M)x4(N) waves, per-wave 128x64 output.
// Round-7 schedule (best measured: 898 TF, MfmaUtil 39%): 8 phases per 2
// K-tiles, one half-tile staged per phase (2 gl_lds/thr), NO mid-phase
// barrier (compiler fine-grained lgkmcnt interleaves ds_read with MFMA;
// 2 waves/SIMD slip within a phase), counted vmcnt(6) at P3/P7 only.
//   P0: Ah1(v)->bv    P1: Ah0(u+2)->bu  P2: Bh0(u+2)->bu  P3: Bh1(u+2)->bu
//   P4: Ah1(u+2)->bu  P5: Ah0(v+2)->bv  P6: Bh0(v+2)->bv  P7: Bh1(v+2)->bv
// vmcnt(6)@P3: retires prev-P5..P7 + P0 => tile v fully published pre-P4.
// vmcnt(6)@P7: retires P1..P4 => tile u+2 published pre-next-P0.
// In-flight 6..14 loads, never drained to 0 (T4). Requires nt even (K=2048).
// LDS swizzle (T2): linear gl_lds dest + inverse-swizzled GLOBAL source
// (colblk ^= row&7) + same XOR on ds_read address (rule #21 involution).
// MODE 0: fp32 C[r*ldc+c]  = alpha*acc        (z-strided)
// MODE 1: bf16 C[r*ldc+c]  = alpha*acc        (z-strided)
// MODE 3: fp32 C[r*ldc+c]  = acc + bias[c]
// MODE 4: fp32 C[r*ldc+c] += alpha*acc        (z-strided)
// MODE 6: bf16 C[r*ldc+c]  = bf16(C + alpha*acc)   (z-strided RMW)
// MODE 5: fused QKV routing, QS=strideC elements per slab:
//         c<2048:  C[r*2048+c]                      (Q [b][n][d])
//         c<4096:  C[QS + r*2048 + (c-2048)]        (K [b][n][d])
//         else:    C[2*QS + (r>>11)*4194304 + (c-4096)*2048 + (r&2047)] (V^T)
template <int MODE>
__global__ __launch_bounds__(512, 2) void gemm256(
    const ushort_t* __restrict__ Abase, const ushort_t* __restrict__ Bbase,
    void* __restrict__ Cbase, const float* __restrict__ bias,
    int K, int lda, int ldb, int ldc,
    long strideA, long strideB, long strideC, float alpha) {
  __shared__ alignas(16) ushort_t sAB[2][2][256 * 64];

  const int z = blockIdx.z;
  const ushort_t* A = Abase + (long)z * strideA;
  const ushort_t* B = Bbase + (long)z * strideB;

  // bijective XCD swizzle (m204): contiguous chunk of flat ids per XCD.
  int bx, by;
  {
    const int gx = gridDim.x;
    const int nwg = gx * gridDim.y;
    const int f = blockIdx.x + gx * blockIdx.y;
    const int q = nwg >> 3, r = nwg & 7;
    const int xcd = f & 7, idx = f >> 3;
    const int fs = (xcd < r ? xcd * (q + 1) : r * (q + 1) + (xcd - r) * q) + idx;
    bx = fs % gx;
    by = fs / gx;
  }
  const int row0 = by * 256;  // M
  const int col0 = bx * 256;  // N

  const int tid  = threadIdx.x;
  const int lane = tid & 63;
  const int wave = tid >> 6;  // 0..7
  const int wm   = wave >> 2; // 0..1
  const int wn   = wave & 3;  // 0..3

  const int fr = lane & 15;   // row-in-16 for fragment reads
  const int kq = lane >> 4;   // k-octet 0..3

  // staging lane geometry: within one gl_lds (1 KiB = 8 rows x 128 B),
  // lane l -> row (l>>3), colblk (l&7). Pre-swizzle the GLOBAL colblk.
  const int srow = lane >> 3;                 // row&7 of this lane's slice
  const int scol = ((lane & 7) ^ srow) * 8;   // inverse-swizzled col (elems)

  // ds_read swizzled column offsets (elements), ks = k-sub (0: k0..31, 1: k32..63)
  const int kx0 = ((kq << 3)) ^ ((fr & 7) << 3);
  const int kx1 = ((1 << 5) | (kq << 3)) ^ ((fr & 7) << 3);

  // per-thread global staging bases (chunk row added per call)
  const ushort_t* Ag = A + (long)(row0 + srow) * lda + scol;
  const ushort_t* Bg = B + (long)(col0 + srow) * ldb + scol;

  const floatx4 zero4 = {0.f, 0.f, 0.f, 0.f};
  floatx4 acc[8][4];
#pragma unroll
  for (int a = 0; a < 8; ++a)
#pragma unroll
    for (int b = 0; b < 4; ++b) acc[a][b] = zero4;

  const int nt = K >> 6;  // K-tiles of 64 (must be even)

  // half-tile stagers: 2 gl_lds per thread = 16 KB block-wide.
  // A half h: rows {h*64..+63} and {128+h*64..+63}  (af reads for qm=h)
  auto stA = [&](long kk, int buf, int h) {
#pragma unroll
    for (int c = 0; c < 2; ++c) {
      const int rb = c * 128 + h * 64 + wave * 8;
      gl_lds16(Ag + (long)rb * lda + kk, &sAB[buf][0][rb * 64]);
    }
  };
  // B half h: rows with bit5==h, i.e. (g>>2)*64 + h*32 + (g&3)*8, g=c*8+wave
  auto stB = [&](long kk, int buf, int h) {
#pragma unroll
    for (int c = 0; c < 2; ++c) {
      const int g = c * 8 + wave;
      const int rb = (g >> 2) * 64 + h * 32 + (g & 3) * 8;
      gl_lds16(Bg + (long)rb * ldb + kk, &sAB[buf][1][rb * 64]);
    }
  };

  // prologue: tile0 all 4 halves -> buf0; tile1 {Ah0,Bh0,Bh1} -> buf1.
  // vmcnt(6) retires tile0 (8 loads), leaves tile1's 3 halves in flight.
  stA(0, 0, 0); stA(0, 0, 1); stB(0, 0, 0); stB(0, 0, 1);
  stA(64, 1, 0); stB(64, 1, 0); stB(64, 1, 1);
  VM6();
  BAR();

#define RD_AF(SRC, QM)                                                        \
  _Pragma("unroll") for (int mi = 0; mi < 4; ++mi) {                          \
    const int rowb = (wm * 128 + (QM)*64 + mi * 16 + fr) * 64;                \
    af[mi][0] = *(const bf16x8*)&(SRC)[rowb + kx0];                           \
    af[mi][1] = *(const bf16x8*)&(SRC)[rowb + kx1];                           \
  }
#define RD_BQ(DST, SRC, QN)                                                   \
  _Pragma("unroll") for (int nj = 0; nj < 2; ++nj) {                          \
    const int rowb = (wn * 64 + (QN)*32 + nj * 16 + fr) * 64;                 \
    DST[nj][0] = *(const bf16x8*)&(SRC)[rowb + kx0];                          \
    DST[nj][1] = *(const bf16x8*)&(SRC)[rowb + kx1];                          \
  }
#define MFMA_Q(QM, QN, BQ)                                                    \
  _Pragma("unroll") for (int mi = 0; mi < 4; ++mi)                            \
  _Pragma("unroll") for (int nj = 0; nj < 2; ++nj)                            \
  _Pragma("unroll") for (int ks = 0; ks < 2; ++ks)                            \
      acc[(QM)*4 + mi][(QN)*2 + nj] = __builtin_amdgcn_mfma_f32_16x16x32_bf16( \
          af[mi][ks], BQ[nj][ks], acc[(QM)*4 + mi][(QN)*2 + nj], 0, 0, 0);
#define PRIO1() __builtin_amdgcn_s_setprio(1)
#define PRIO0() __builtin_amdgcn_s_setprio(0)

  const long kl = (long)(nt - 1) << 6;  // clamp (stale writes land in dead regions)
  const int niter = nt >> 1;
  const ushort_t* sAu = sAB[0][0];
  const ushort_t* sBu = sAB[0][1];
  const ushort_t* sAv = sAB[1][0];
  const ushort_t* sBv = sAB[1][1];

  for (int i = 0; i < niter; ++i) {
    const long kv = (long)(2 * i + 1) << 6;
    long ku2 = (long)(2 * i + 2) << 6; if (ku2 > kl) ku2 = kl;
    long kv2 = (long)(2 * i + 3) << 6; if (kv2 > kl) kv2 = kl;
    bf16x8 af[4][2], bq0[2][2], bq1[2][2];

    // ---- P0: u quadrant (0,0); stage Ah1(v)->bv [died prev P6]
    RD_AF(sAu, 0); RD_BQ(bq0, sBu, 0);
    stA(kv, 1, 1);
    PRIO1(); MFMA_Q(0, 0, bq0); PRIO0(); BAR();

    // ---- P1: u quadrant (0,1); stage Ah0(u+2)->bu [died P0]
    RD_BQ(bq1, sBu, 1);
    stA(ku2, 0, 0);
    PRIO1(); MFMA_Q(0, 1, bq1); PRIO0(); BAR();

    // ---- P2: u quadrant (1,1); stage Bh0(u+2)->bu [died P0]
    RD_AF(sAu, 1);
    stB(ku2, 0, 0);
    PRIO1(); MFMA_Q(1, 1, bq1); PRIO0(); BAR();

    // ---- P3: u quadrant (1,0) (regs only); stage Bh1(u+2)->bu [died P1]
    stB(ku2, 0, 1);
    PRIO1(); MFMA_Q(1, 0, bq0); PRIO0();
    VM6();  // retires prev-P5..P7 + P0 => tile v fully published
    BAR();

    // ---- P4: v quadrant (0,0); stage Ah1(u+2)->bu [died P2]
    RD_AF(sAv, 0); RD_BQ(bq0, sBv, 0);
    stA(ku2, 0, 1);
    PRIO1(); MFMA_Q(0, 0, bq0); PRIO0(); BAR();

    // ---- P5: v quadrant (0,1); stage Ah0(v+2)->bv [died P4]
    RD_BQ(bq1, sBv, 1);
    stA(kv2, 1, 0);
    PRIO1(); MFMA_Q(0, 1, bq1); PRIO0(); BAR();

    // ---- P6: v quadrant (1,1); stage Bh0(v+2)->bv [died P4]
    RD_AF(sAv, 1);
    stB(kv2, 1, 0);
    PRIO1(); MFMA_Q(1, 1, bq1); PRIO0(); BAR();

    // ---- P7: v quadrant (1,0); stage Bh1(v+2)->bv [died P5]
    stB(kv2, 1, 1);
    PRIO1(); MFMA_Q(1, 0, bq0); PRIO0();
    VM6();  // retires P1..P4 => tile u+2 fully published
    BAR();
  }
#undef RD_AF
#undef RD_BQ
#undef MFMA_Q

  // C/D layout: col = lane&15, row = (lane>>4)*4 + reg   [verified m89/m91]
  const int ccol  = lane & 15;
  const int crow4 = (lane >> 4) * 4;

  if (MODE == 0 || MODE == 3 || MODE == 4) {
    float* C = (float*)Cbase + (long)z * strideC;
#pragma unroll
    for (int a = 0; a < 8; ++a) {
      const int rbase = row0 + wm * 128 + (a >> 2) * 64 + (a & 3) * 16 + crow4;
#pragma unroll
      for (int b = 0; b < 4; ++b) {
        const int c = col0 + wn * 64 + (b >> 1) * 32 + (b & 1) * 16 + ccol;
        const float bb = (MODE == 3) ? bias[c] : 0.f;
#pragma unroll
        for (int r = 0; r < 4; ++r) {
          const long idx = (long)(rbase + r) * ldc + c;
          float v;
          if (MODE == 3)      v = acc[a][b][r] + bb;
          else if (MODE == 4) v = C[idx] + alpha * acc[a][b][r];
          else                v = alpha * acc[a][b][r];
          C[idx] = v;
        }
      }
    }
  } else if (MODE == 1 || MODE == 6) {
    ushort_t* C = (ushort_t*)Cbase + (long)z * strideC;
#pragma unroll
    for (int a = 0; a < 8; ++a) {
      const int rbase = row0 + wm * 128 + (a >> 2) * 64 + (a & 3) * 16 + crow4;
#pragma unroll
      for (int b = 0; b < 4; ++b) {
        const int c = col0 + wn * 64 + (b >> 1) * 32 + (b & 1) * 16 + ccol;
#pragma unroll
        for (int r = 0; r < 4; ++r) {
          const long idx = (long)(rbase + r) * ldc + c;
          float v = alpha * acc[a][b][r];
          if (MODE == 6) v += bf2f(C[idx]);
          C[idx] = f2bf(v);
        }
      }
    }
  } else {  // MODE 5
    ushort_t* C = (ushort_t*)Cbase;
    const long QS = strideC;
#pragma unroll
    for (int a = 0; a < 8; ++a) {
      const int rbase = row0 + wm * 128 + (a >> 2) * 64 + (a & 3) * 16 + crow4;
#pragma unroll
      for (int b = 0; b < 4; ++b) {
        const int c = col0 + wn * 64 + (b >> 1) * 32 + (b & 1) * 16 + ccol;
#pragma unroll
        for (int r = 0; r < 4; ++r) {
          const int rr = rbase + r;
          const ushort_t v = f2bf(acc[a][b][r]);
          if (c < 2048)
            C[(long)rr * 2048 + c] = v;
          else if (c < 4096)
            C[QS + (long)rr * 2048 + (c - 2048)] = v;
          else
            C[2 * QS + (long)(rr >> 11) * 4194304 + (long)(c - 4096) * 2048 +
              (rr & 2047)] = v;
        }
      }
    }
  }
}

// ---------------- online column softmax (over query axis n) ----------------
// BF16IN=1: S is bf16 (ushort); else fp32. Output w always bf16.
template <int BF16IN>
__global__ void softmax_cols(const void* __restrict__ Sbase,
                             ushort_t* __restrict__ wbase) {
  __shared__ float rmx[8][32], rsum[8][32];
  const long zoff = (long)blockIdx.y * 4194304;
  const int tx = threadIdx.x & 31;
  const int ty = threadIdx.x >> 5;
  const int m = blockIdx.x * 32 + tx;
  const float* Sf = (const float*)Sbase + zoff + m;
  const ushort_t* Sh = (const ushort_t*)Sbase + zoff + m;
  const int n0 = ty * 256;

  auto rd = [&](int n) -> float {
    if (BF16IN) return bf2f(Sh[(long)n * 2048]);
    return Sf[(long)n * 2048];
  };

  float mx = -3.0e38f, sum = 0.f;
#pragma unroll 4
  for (int n = n0; n < n0 + 256; ++n) {
    const float v = rd(n);
    if (v > mx) {
      sum = sum * __expf(mx - v) + 1.f;
      mx = v;
    } else {
      sum += __expf(v - mx);
    }
  }
  rmx[ty][tx] = mx;
  rsum[ty][tx] = sum;
  __syncthreads();
  float gm = rmx[0][tx];
#pragma unroll
  for (int s = 1; s < 8; ++s) gm = fmaxf(gm, rmx[s][tx]);
  float gs = 0.f;
#pragma unroll
  for (int s = 0; s < 8; ++s) gs += rsum[s][tx] * __expf(rmx[s][tx] - gm);
  const float inv = 1.f / gs;

  ushort_t* wm_ = wbase + zoff + m;
#pragma unroll 4
  for (int n = n0; n < n0 + 256; ++n)
    wm_[(long)n * 2048] = f2bf(__expf(rd(n) - gm) * inv);
}

extern "C" void kernel_launch(void* const* d_in, const int* in_sizes, int n_in,
                              void* d_out, int out_size, void* d_ws,
                              size_t ws_size, hipStream_t stream) {
  const float* x   = (const float*)d_in[0];
  const float* Wq  = (const float*)d_in[1];
  const float* Wk  = (const float*)d_in[2];
  const float* Wv  = (const float*)d_in[3];
  const float* fcw = (const float*)d_in[4];
  const float* fcb = (const float*)d_in[5];
  float* out = (float*)d_out;

  char* ws = (char*)d_ws;
  size_t off = 0;
  auto alloc = [&](size_t bytes) {
    char* p = ws + off;
    off += (bytes + 255) & ~(size_t)255;
    return p;
  };
  const long SL = 4194304L;  // 2048*2048 elements
  const dim3 blk(256);
  const dim3 blk512(512);
  const float scale = 0.022097086912079608f;  // 1/sqrt(2048)

  // persistent
  ushort_t* xb   = (ushort_t*)alloc(33554432);  // x bf16 [8192][2048]
  ushort_t* fcwb = (ushort_t*)alloc(8388608);   // fc_w bf16
  char* loop0 = ws + off;

  cvt_f32_bf16<<<16384, blk, 0, stream>>>(x, xb, 16777216L);
  cvt_f32_bf16<<<4096, blk, 0, stream>>>(fcw, fcwb, 4194304L);

  // Layout A (batched over all b): 234,881,024 bytes total (same as before:
  // S fp32 64MB swapped for S bf16 32MB + persistent meanbP 32MB).
  const bool big = ws_size >= 234881024ULL;

  if (big) {
    ushort_t* meanbP = (ushort_t*)alloc(33554432);  // bf16 head-mean acc [4][2048][2048]
    ushort_t* Wcat = (ushort_t*)alloc(25165824);    // [6144][2048] bf16
    ushort_t* Qh   = (ushort_t*)alloc(33554432);    // [4][2048][2048]
    ushort_t* Kh   = (ushort_t*)alloc(33554432);    // contiguous after Qh
    ushort_t* Vth  = (ushort_t*)alloc(33554432);    // [4][2048 d][2048 m]
    ushort_t* Sb   = (ushort_t*)alloc(33554432);    // scores bf16 [4][2048][2048]
    ushort_t* wc   = Qh;                            // overlay (Q dead post-scores)
    (void)Kh; (void)Vth;

    for (int h = 0; h < 3; ++h) {
      cvt_f32_bf16<<<4096, blk, 0, stream>>>(Wq + h * SL, Wcat, SL);
      cvt_f32_bf16<<<4096, blk, 0, stream>>>(Wk + h * SL, Wcat + SL, SL);
      cvt_f32_bf16<<<4096, blk, 0, stream>>>(Wv + h * SL, Wcat + 2 * SL, SL);

      // fused QKV projection: M=8192, N=6144; QS slab = 16777216 elements
      gemm256<5><<<dim3(24, 32), blk512, 0, stream>>>(
          xb, Wcat, Qh, nullptr, 2048, 2048, 2048, 2048,
          0L, 0L, 16777216L, 1.0f);
      // scores -> bf16, batched z=b
      gemm256<1><<<dim3(8, 8, 4), blk512, 0, stream>>>(
          Qh, Qh + 16777216L, Sb, nullptr, 2048, 2048, 2048, 2048,
          SL, SL, SL, scale);
      softmax_cols<1><<<dim3(64, 4), blk, 0, stream>>>(Sb, wc);
      // meanbP[b] (+)= (1/3) * wc[b] @ Vth[b]^T   (bf16 accumulate)
      if (h == 0)
        gemm256<1><<<dim3(8, 8, 4), blk512, 0, stream>>>(
            wc, Qh + 33554432L, meanbP, nullptr, 2048, 2048, 2048, 2048,
            SL, SL, SL, 1.0f / 3.0f);
      else
        gemm256<6><<<dim3(8, 8, 4), blk512, 0, stream>>>(
            wc, Qh + 33554432L, meanbP, nullptr, 2048, 2048, 2048, 2048,
            SL, SL, SL, 1.0f / 3.0f);
    }

    // out = meanbP @ fc_w^T + fc_b   (no mean cvt pass; d_out untouched till here)
    gemm256<3><<<dim3(8, 32), blk512, 0, stream>>>(
        meanbP, fcwb, out, fcb, 2048, 2048, 2048, 2048,
        0L, 0L, 0L, 1.0f);
  } else {
    // compact: exact round-3 footprint (109,051,904 bytes; proven safe).
    // Kept byte-identical to the verified round-7 path (unknown ws bound).
    float* mean32 = out;  // fp32 head-sum accumulator in d_out
    ushort_t* Wqh  = (ushort_t*)alloc(8388608);  // [2048][2048] -+
    ushort_t* Wkh  = (ushort_t*)alloc(8388608);  //               | contiguous
    ushort_t* Wvh  = (ushort_t*)alloc(8388608);  //              -+ = [6144][2048]
    ushort_t* Qhb  = (ushort_t*)alloc(8388608);  // [2048][2048] -+
    ushort_t* Khb  = (ushort_t*)alloc(8388608);  //               | contiguous
    ushort_t* Vthb = (ushort_t*)alloc(8388608);  //              -+
    float*    S    = (float*)alloc(16777216);    // [2048][2048] fp32
    ushort_t* wchb = Qhb;                        // overlay
    (void)Wkh; (void)Wvh; (void)Khb; (void)Vthb;

    for (int h = 0; h < 3; ++h) {
      cvt_f32_bf16<<<4096, blk, 0, stream>>>(Wq + h * SL, Wqh, SL);
      cvt_f32_bf16<<<4096, blk, 0, stream>>>(Wk + h * SL, Wqh + SL, SL);
      cvt_f32_bf16<<<4096, blk, 0, stream>>>(Wv + h * SL, Wqh + 2 * SL, SL);

      for (int b = 0; b < 4; ++b) {
        const ushort_t* xbb = xb + b * SL;
        // fused QKV projection: M=2048, N=6144; QS slab = 4194304 elements
        gemm256<5><<<dim3(24, 8), blk512, 0, stream>>>(
            xbb, Wqh, Qhb, nullptr, 2048, 2048, 2048, 2048,
            0L, 0L, 4194304L, 1.0f);
        gemm256<0><<<dim3(8, 8), blk512, 0, stream>>>(
            Qhb, Qhb + SL, S, nullptr, 2048, 2048, 2048, 2048,
            0L, 0L, 0L, scale);
        softmax_cols<0><<<dim3(64, 1), blk, 0, stream>>>(S, wchb);
        if (h == 0)
          gemm256<0><<<dim3(8, 8), blk512, 0, stream>>>(
              wchb, Qhb + 2 * SL, mean32 + b * SL, nullptr, 2048,
              2048, 2048, 2048, 0L, 0L, 0L, 1.0f / 3.0f);
        else
          gemm256<4><<<dim3(8, 8), blk512, 0, stream>>>(
              wchb, Qhb + 2 * SL, mean32 + b * SL, nullptr, 2048,
              2048, 2048, 2048, 0L, 0L, 0L, 1.0f / 3.0f);
      }
    }

    // mean (in d_out) -> bf16 overlay in loop region, then FC
    ushort_t* meanb = (ushort_t*)loop0;
    cvt_f32_bf16<<<16384, blk, 0, stream>>>(mean32, meanb, 16777216L);
    gemm256<3><<<dim3(8, 32), blk512, 0, stream>>>(
        meanb, fcwb, out, fcb, 2048, 2048, 2048, 2048,
        0L, 0L, 0L, 1.0f);
  }
}

// Round 10
// 1563.826 us; speedup vs baseline: 1.2240x; 1.0687x over previous
//
#include <hip/hip_runtime.h>
#include <stdint.h>

typedef __attribute__((ext_vector_type(4))) float floatx4;
typedef __bf16 bf16x8 __attribute__((ext_vector_type(8)));
typedef unsigned short ushort_t;

// float -> bf16 round-to-nearest-even (raw bits)
__device__ __forceinline__ ushort_t f2bf(float f) {
  unsigned u = __float_as_uint(f);
  u += 0x7FFFu + ((u >> 16) & 1u);
  return (ushort_t)(u >> 16);
}
__device__ __forceinline__ float bf2f(ushort_t h) {
  return __uint_as_float((unsigned)h << 16);
}

// async global->LDS, 16B per lane. LDS dest is wave-uniform base + lane*16.
__device__ __forceinline__ void gl_lds16(const void* g, void* l) {
  __builtin_amdgcn_global_load_lds(
      (__attribute__((address_space(1))) void*)g,
      (__attribute__((address_space(3))) void*)l, 16, 0, 0);
}

// raw barrier WITHOUT waitcnt drain; counted vmcnt keeps loads in flight
// across barriers (T4). asm memory clobber fences compiler code motion.
#define BAR() asm volatile("s_barrier" ::: "memory")
#define VM6() asm volatile("s_waitcnt vmcnt(6)" ::: "memory")

// ---------------- fp32 -> bf16 conversion (vectorized) ----------------
__global__ void cvt_f32_bf16(const float* __restrict__ src,
                             ushort_t* __restrict__ dst, long n) {
  long i = ((long)blockIdx.x * 256 + threadIdx.x) * 4;
  if (i >= n) return;
  float4 v = *(const float4*)(src + i);
  ushort4 o;
  o.x = f2bf(v.x); o.y = f2bf(v.y); o.z = f2bf(v.z); o.w = f2bf(v.w);
  *(ushort4*)(dst + i) = o;
}

// 3-source fused cvt: blockIdx.y selects src; dst slab = y*n_each.
__global__ void cvt3_f32_bf16(const float* __restrict__ s0,
                              const float* __restrict__ s1,
                              const float* __restrict__ s2,
                              ushort_t* __restrict__ dst, long n_each) {
  const float* s = (blockIdx.y == 0) ? s0 : (blockIdx.y == 1 ? s1 : s2);
  long i = ((long)blockIdx.x * 256 + threadIdx.x) * 4;
  if (i >= n_each) return;
  float4 v = *(const float4*)(s + i);
  ushort4 o;
  o.x = f2bf(v.x); o.y = f2bf(v.y); o.z = f2bf(v.z); o.w = f2bf(v.w);
  *(ushort4*)(dst + (long)blockIdx.y * n_each + i) = o;
}

// ---------------- bf16 GEMM, C = alpha * A * B^T (+bias) ----------------
// 256x256 tile, BK=64, 512 thr = 2(M)x4(N) waves, per-wave 128x64 output.
// Round-7 schedule (best measured: 898 TF, MfmaUtil 39%): 8 phases per 2
// K-tiles, one half-tile staged per phase (2 gl_lds/thr), NO mid-phase
// barrier (compiler fine-grained lgkmcnt interleaves ds_read with MFMA;
// 2 waves/SIMD slip within a phase), counted vmcnt(6) at P3/P7 only.
//   P0: Ah1(v)->bv    P1: Ah0(u+2)->bu  P2: Bh0(u+2)->bu  P3: Bh1(u+2)->bu
//   P4: Ah1(u+2)->bu  P5: Ah0(v+2)->bv  P6: Bh0(v+2)->bv  P7: Bh1(v+2)->bv
// vmcnt(6)@P3: retires prev-P5..P7 + P0 => tile v fully published pre-P4.
// vmcnt(6)@P7: retires P1..P4 => tile u+2 published pre-next-P0.
// In-flight 6..14 loads, never drained to 0 (T4). Requires nt even (K=2048).
// LDS swizzle (T2): linear gl_lds dest + inverse-swizzled GLOBAL source
// (colblk ^= row&7) + same XOR on ds_read address (rule #21 involution).
// MODE 0: fp32 C[r*ldc+c]  = alpha*acc        (z-strided)
// MODE 1: bf16 C[r*ldc+c]  = alpha*acc        (z-strided)
// MODE 3: fp32 C[r*ldc+c]  = acc + bias[c]
// MODE 4: fp32 C[r*ldc+c] += alpha*acc        (z-strided)
// MODE 6: bf16 C[r*ldc+c]  = bf16(C + alpha*acc)   (z-strided RMW)
// MODE 5: fused QKV routing, QS=strideC elements per slab:
//         c<2048:  C[r*2048+c]                      (Q [b][n][d])
//         c<4096:  C[QS + r*2048 + (c-2048)]        (K [b][n][d])
//         else:    C[2*QS + (r>>11)*4194304 + (c-4096)*2048 + (r&2047)] (V^T)
template <int MODE>
__global__ __launch_bounds__(512, 2) void gemm256(
    const ushort_t* __restrict__ Abase, const ushort_t* __restrict__ Bbase,
    void* __restrict__ Cbase, const float* __restrict__ bias,
    int K, int lda, int ldb, int ldc,
    long strideA, long strideB, long strideC, float alpha) {
  __shared__ alignas(16) ushort_t sAB[2][2][256 * 64];

  const int z = blockIdx.z;
  const ushort_t* A = Abase + (long)z * strideA;
  const ushort_t* B = Bbase + (long)z * strideB;

  // bijective XCD swizzle (m204): contiguous chunk of flat ids per XCD.
  int bx, by;
  {
    const int gx = gridDim.x;
    const int nwg = gx * gridDim.y;
    const int f = blockIdx.x + gx * blockIdx.y;
    const int q = nwg >> 3, r = nwg & 7;
    const int xcd = f & 7, idx = f >> 3;
    const int fs = (xcd < r ? xcd * (q + 1) : r * (q + 1) + (xcd - r) * q) + idx;
    bx = fs % gx;
    by = fs / gx;
  }
  const int row0 = by * 256;  // M
  const int col0 = bx * 256;  // N

  const int tid  = threadIdx.x;
  const int lane = tid & 63;
  const int wave = tid >> 6;  // 0..7
  const int wm   = wave >> 2; // 0..1
  const int wn   = wave & 3;  // 0..3

  const int fr = lane & 15;   // row-in-16 for fragment reads
  const int kq = lane >> 4;   // k-octet 0..3

  // staging lane geometry: within one gl_lds (1 KiB = 8 rows x 128 B),
  // lane l -> row (l>>3), colblk (l&7). Pre-swizzle the GLOBAL colblk.
  const int srow = lane >> 3;                 // row&7 of this lane's slice
  const int scol = ((lane & 7) ^ srow) * 8;   // inverse-swizzled col (elems)

  // ds_read swizzled column offsets (elements), ks = k-sub (0: k0..31, 1: k32..63)
  const int kx0 = ((kq << 3)) ^ ((fr & 7) << 3);
  const int kx1 = ((1 << 5) | (kq << 3)) ^ ((fr & 7) << 3);

  // per-thread global staging bases (chunk row added per call)
  const ushort_t* Ag = A + (long)(row0 + srow) * lda + scol;
  const ushort_t* Bg = B + (long)(col0 + srow) * ldb + scol;

  const floatx4 zero4 = {0.f, 0.f, 0.f, 0.f};
  floatx4 acc[8][4];
#pragma unroll
  for (int a = 0; a < 8; ++a)
#pragma unroll
    for (int b = 0; b < 4; ++b) acc[a][b] = zero4;

  const int nt = K >> 6;  // K-tiles of 64 (must be even)

  // half-tile stagers: 2 gl_lds per thread = 16 KB block-wide.
  // A half h: rows {h*64..+63} and {128+h*64..+63}  (af reads for qm=h)
  auto stA = [&](long kk, int buf, int h) {
#pragma unroll
    for (int c = 0; c < 2; ++c) {
      const int rb = c * 128 + h * 64 + wave * 8;
      gl_lds16(Ag + (long)rb * lda + kk, &sAB[buf][0][rb * 64]);
    }
  };
  // B half h: rows with bit5==h, i.e. (g>>2)*64 + h*32 + (g&3)*8, g=c*8+wave
  auto stB = [&](long kk, int buf, int h) {
#pragma unroll
    for (int c = 0; c < 2; ++c) {
      const int g = c * 8 + wave;
      const int rb = (g >> 2) * 64 + h * 32 + (g & 3) * 8;
      gl_lds16(Bg + (long)rb * ldb + kk, &sAB[buf][1][rb * 64]);
    }
  };

  // prologue: tile0 all 4 halves -> buf0; tile1 {Ah0,Bh0,Bh1} -> buf1.
  // vmcnt(6) retires tile0 (8 loads), leaves tile1's 3 halves in flight.
  stA(0, 0, 0); stA(0, 0, 1); stB(0, 0, 0); stB(0, 0, 1);
  stA(64, 1, 0); stB(64, 1, 0); stB(64, 1, 1);
  VM6();
  BAR();

#define RD_AF(SRC, QM)                                                        \
  _Pragma("unroll") for (int mi = 0; mi < 4; ++mi) {                          \
    const int rowb = (wm * 128 + (QM)*64 + mi * 16 + fr) * 64;                \
    af[mi][0] = *(const bf16x8*)&(SRC)[rowb + kx0];                           \
    af[mi][1] = *(const bf16x8*)&(SRC)[rowb + kx1];                           \
  }
#define RD_BQ(DST, SRC, QN)                                                   \
  _Pragma("unroll") for (int nj = 0; nj < 2; ++nj) {                          \
    const int rowb = (wn * 64 + (QN)*32 + nj * 16 + fr) * 64;                 \
    DST[nj][0] = *(const bf16x8*)&(SRC)[rowb + kx0];                          \
    DST[nj][1] = *(const bf16x8*)&(SRC)[rowb + kx1];                          \
  }
#define MFMA_Q(QM, QN, BQ)                                                    \
  _Pragma("unroll") for (int mi = 0; mi < 4; ++mi)                            \
  _Pragma("unroll") for (int nj = 0; nj < 2; ++nj)                            \
  _Pragma("unroll") for (int ks = 0; ks < 2; ++ks)                            \
      acc[(QM)*4 + mi][(QN)*2 + nj] = __builtin_amdgcn_mfma_f32_16x16x32_bf16( \
          af[mi][ks], BQ[nj][ks], acc[(QM)*4 + mi][(QN)*2 + nj], 0, 0, 0);
#define PRIO1() __builtin_amdgcn_s_setprio(1)
#define PRIO0() __builtin_amdgcn_s_setprio(0)

  const long kl = (long)(nt - 1) << 6;  // clamp (stale writes land in dead regions)
  const int niter = nt >> 1;
  const ushort_t* sAu = sAB[0][0];
  const ushort_t* sBu = sAB[0][1];
  const ushort_t* sAv = sAB[1][0];
  const ushort_t* sBv = sAB[1][1];

  for (int i = 0; i < niter; ++i) {
    const long kv = (long)(2 * i + 1) << 6;
    long ku2 = (long)(2 * i + 2) << 6; if (ku2 > kl) ku2 = kl;
    long kv2 = (long)(2 * i + 3) << 6; if (kv2 > kl) kv2 = kl;
    bf16x8 af[4][2], bq0[2][2], bq1[2][2];

    // ---- P0: u quadrant (0,0); stage Ah1(v)->bv [died prev P6]
    RD_AF(sAu, 0); RD_BQ(bq0, sBu, 0);
    stA(kv, 1, 1);
    PRIO1(); MFMA_Q(0, 0, bq0); PRIO0(); BAR();

    // ---- P1: u quadrant (0,1); stage Ah0(u+2)->bu [died P0]
    RD_BQ(bq1, sBu, 1);
    stA(ku2, 0, 0);
    PRIO1(); MFMA_Q(0, 1, bq1); PRIO0(); BAR();

    // ---- P2: u quadrant (1,1); stage Bh0(u+2)->bu [died P0]
    RD_AF(sAu, 1);
    stB(ku2, 0, 0);
    PRIO1(); MFMA_Q(1, 1, bq1); PRIO0(); BAR();

    // ---- P3: u quadrant (1,0) (regs only); stage Bh1(u+2)->bu [died P1]
    stB(ku2, 0, 1);
    PRIO1(); MFMA_Q(1, 0, bq0); PRIO0();
    VM6();  // retires prev-P5..P7 + P0 => tile v fully published
    BAR();

    // ---- P4: v quadrant (0,0); stage Ah1(u+2)->bu [died P2]
    RD_AF(sAv, 0); RD_BQ(bq0, sBv, 0);
    stA(ku2, 0, 1);
    PRIO1(); MFMA_Q(0, 0, bq0); PRIO0(); BAR();

    // ---- P5: v quadrant (0,1); stage Ah0(v+2)->bv [died P4]
    RD_BQ(bq1, sBv, 1);
    stA(kv2, 1, 0);
    PRIO1(); MFMA_Q(0, 1, bq1); PRIO0(); BAR();

    // ---- P6: v quadrant (1,1); stage Bh0(v+2)->bv [died P4]
    RD_AF(sAv, 1);
    stB(kv2, 1, 0);
    PRIO1(); MFMA_Q(1, 1, bq1); PRIO0(); BAR();

    // ---- P7: v quadrant (1,0); stage Bh1(v+2)->bv [died P5]
    stB(kv2, 1, 1);
    PRIO1(); MFMA_Q(1, 0, bq0); PRIO0();
    VM6();  // retires P1..P4 => tile u+2 fully published
    BAR();
  }
#undef RD_AF
#undef RD_BQ
#undef MFMA_Q

  // C/D layout: col = lane&15, row = (lane>>4)*4 + reg   [verified m89/m91]
  const int ccol  = lane & 15;
  const int crow4 = (lane >> 4) * 4;

  if (MODE == 0 || MODE == 3 || MODE == 4) {
    float* C = (float*)Cbase + (long)z * strideC;
#pragma unroll
    for (int a = 0; a < 8; ++a) {
      const int rbase = row0 + wm * 128 + (a >> 2) * 64 + (a & 3) * 16 + crow4;
#pragma unroll
      for (int b = 0; b < 4; ++b) {
        const int c = col0 + wn * 64 + (b >> 1) * 32 + (b & 1) * 16 + ccol;
        const float bb = (MODE == 3) ? bias[c] : 0.f;
#pragma unroll
        for (int r = 0; r < 4; ++r) {
          const long idx = (long)(rbase + r) * ldc + c;
          float v;
          if (MODE == 3)      v = acc[a][b][r] + bb;
          else if (MODE == 4) v = C[idx] + alpha * acc[a][b][r];
          else                v = alpha * acc[a][b][r];
          C[idx] = v;
        }
      }
    }
  } else if (MODE == 1 || MODE == 6) {
    ushort_t* C = (ushort_t*)Cbase + (long)z * strideC;
#pragma unroll
    for (int a = 0; a < 8; ++a) {
      const int rbase = row0 + wm * 128 + (a >> 2) * 64 + (a & 3) * 16 + crow4;
#pragma unroll
      for (int b = 0; b < 4; ++b) {
        const int c = col0 + wn * 64 + (b >> 1) * 32 + (b & 1) * 16 + ccol;
#pragma unroll
        for (int r = 0; r < 4; ++r) {
          const long idx = (long)(rbase + r) * ldc + c;
          float v = alpha * acc[a][b][r];
          if (MODE == 6) v += bf2f(C[idx]);
          C[idx] = f2bf(v);
        }
      }
    }
  } else {  // MODE 5
    ushort_t* C = (ushort_t*)Cbase;
    const long QS = strideC;
#pragma unroll
    for (int a = 0; a < 8; ++a) {
      const int rbase = row0 + wm * 128 + (a >> 2) * 64 + (a & 3) * 16 + crow4;
#pragma unroll
      for (int b = 0; b < 4; ++b) {
        const int c = col0 + wn * 64 + (b >> 1) * 32 + (b & 1) * 16 + ccol;
#pragma unroll
        for (int r = 0; r < 4; ++r) {
          const int rr = rbase + r;
          const ushort_t v = f2bf(acc[a][b][r]);
          if (c < 2048)
            C[(long)rr * 2048 + c] = v;
          else if (c < 4096)
            C[QS + (long)rr * 2048 + (c - 2048)] = v;
          else
            C[2 * QS + (long)(rr >> 11) * 4194304 + (long)(c - 4096) * 2048 +
              (rr & 2047)] = v;
        }
      }
    }
  }
}

// ---------------- online column softmax (over query axis n) ----------------
// v1 (scalar, fp32 or bf16 input) -- kept for the compact branch.
template <int BF16IN>
__global__ void softmax_cols(const void* __restrict__ Sbase,
                             ushort_t* __restrict__ wbase) {
  __shared__ float rmx[8][32], rsum[8][32];
  const long zoff = (long)blockIdx.y * 4194304;
  const int tx = threadIdx.x & 31;
  const int ty = threadIdx.x >> 5;
  const int m = blockIdx.x * 32 + tx;
  const float* Sf = (const float*)Sbase + zoff + m;
  const ushort_t* Sh = (const ushort_t*)Sbase + zoff + m;
  const int n0 = ty * 256;

  auto rd = [&](int n) -> float {
    if (BF16IN) return bf2f(Sh[(long)n * 2048]);
    return Sf[(long)n * 2048];
  };

  float mx = -3.0e38f, sum = 0.f;
#pragma unroll 4
  for (int n = n0; n < n0 + 256; ++n) {
    const float v = rd(n);
    if (v > mx) {
      sum = sum * __expf(mx - v) + 1.f;
      mx = v;
    } else {
      sum += __expf(v - mx);
    }
  }
  rmx[ty][tx] = mx;
  rsum[ty][tx] = sum;
  __syncthreads();
  float gm = rmx[0][tx];
#pragma unroll
  for (int s = 1; s < 8; ++s) gm = fmaxf(gm, rmx[s][tx]);
  float gs = 0.f;
#pragma unroll
  for (int s = 0; s < 8; ++s) gs += rsum[s][tx] * __expf(rmx[s][tx] - gm);
  const float inv = 1.f / gs;

  ushort_t* wm_ = wbase + zoff + m;
#pragma unroll 4
  for (int n = n0; n < n0 + 256; ++n)
    wm_[(long)n * 2048] = f2bf(__expf(rd(n) - gm) * inv);
}

// v2 (vectorized, bf16 in/out): block = 8 col-groups x 32 strips; each
// thread owns 8 columns (one bf16x8 = 16B per row access, G13), 64 rows per
// strip. LDS strip-reduce (32 strips x 64 cols), redundant global reduce in
// registers, pass-2 writes bf16x8. Grid (32, z): 64 cols x 2048 rows/block.
__global__ void softmax_cols_v2(const ushort_t* __restrict__ Sbase,
                                ushort_t* __restrict__ wbase) {
  __shared__ float smx[32][64];
  __shared__ float ssm[32][64];
  const long zoff = (long)blockIdx.y * 4194304;
  const int tg = threadIdx.x & 7;    // col-group 0..7
  const int ty = threadIdx.x >> 3;   // strip 0..31
  const int mc = tg * 8;             // col offset in block (0..56)
  const ushort_t* Sp = Sbase + zoff + blockIdx.x * 64 + mc;
  const int n0 = ty * 64;

  float mx[8], sm[8];
#pragma unroll
  for (int j = 0; j < 8; ++j) { mx[j] = -3.0e38f; sm[j] = 0.f; }

  for (int n = n0; n < n0 + 64; ++n) {
    bf16x8 v8 = *(const bf16x8*)(Sp + (long)n * 2048);
#pragma unroll
    for (int j = 0; j < 8; ++j) {
      const float v = (float)v8[j];
      if (v > mx[j]) {
        sm[j] = sm[j] * __expf(mx[j] - v) + 1.f;
        mx[j] = v;
      } else {
        sm[j] += __expf(v - mx[j]);
      }
    }
  }
#pragma unroll
  for (int j = 0; j < 8; ++j) { smx[ty][mc + j] = mx[j]; ssm[ty][mc + j] = sm[j]; }
  __syncthreads();

  float gm[8], gi[8];
#pragma unroll
  for (int j = 0; j < 8; ++j) {
    const int c = mc + j;
    float g = smx[0][c];
    for (int s = 1; s < 32; ++s) g = fmaxf(g, smx[s][c]);
    float Z = 0.f;
    for (int s = 0; s < 32; ++s) Z += ssm[s][c] * __expf(smx[s][c] - g);
    gm[j] = g;
    gi[j] = 1.f / Z;
  }

  ushort_t* wp = wbase + zoff + blockIdx.x * 64 + mc;
  for (int n = n0; n < n0 + 64; ++n) {
    bf16x8 v8 = *(const bf16x8*)(Sp + (long)n * 2048);
    bf16x8 o8;
#pragma unroll
    for (int j = 0; j < 8; ++j)
      o8[j] = (__bf16)(__expf((float)v8[j] - gm[j]) * gi[j]);
    *(bf16x8*)(wp + (long)n * 2048) = o8;
  }
}

extern "C" void kernel_launch(void* const* d_in, const int* in_sizes, int n_in,
                              void* d_out, int out_size, void* d_ws,
                              size_t ws_size, hipStream_t stream) {
  const float* x   = (const float*)d_in[0];
  const float* Wq  = (const float*)d_in[1];
  const float* Wk  = (const float*)d_in[2];
  const float* Wv  = (const float*)d_in[3];
  const float* fcw = (const float*)d_in[4];
  const float* fcb = (const float*)d_in[5];
  float* out = (float*)d_out;

  char* ws = (char*)d_ws;
  size_t off = 0;
  auto alloc = [&](size_t bytes) {
    char* p = ws + off;
    off += (bytes + 255) & ~(size_t)255;
    return p;
  };
  const long SL = 4194304L;  // 2048*2048 elements
  const dim3 blk(256);
  const dim3 blk512(512);
  const float scale = 0.022097086912079608f;  // 1/sqrt(2048)

  // persistent
  ushort_t* xb   = (ushort_t*)alloc(33554432);  // x bf16 [8192][2048]
  ushort_t* fcwb = (ushort_t*)alloc(8388608);   // fc_w bf16
  char* loop0 = ws + off;

  cvt_f32_bf16<<<16384, blk, 0, stream>>>(x, xb, 16777216L);
  cvt_f32_bf16<<<4096, blk, 0, stream>>>(fcw, fcwb, 4194304L);

  // Layout A (batched over all b): 234,881,024 bytes total.
  const bool big = ws_size >= 234881024ULL;

  if (big) {
    ushort_t* meanbP = (ushort_t*)alloc(33554432);  // bf16 head-mean acc [4][2048][2048]
    ushort_t* Wcat = (ushort_t*)alloc(25165824);    // [6144][2048] bf16
    ushort_t* Qh   = (ushort_t*)alloc(33554432);    // [4][2048][2048]
    ushort_t* Kh   = (ushort_t*)alloc(33554432);    // contiguous after Qh
    ushort_t* Vth  = (ushort_t*)alloc(33554432);    // [4][2048 d][2048 m]
    ushort_t* Sb   = (ushort_t*)alloc(33554432);    // scores bf16 [4][2048][2048]
    ushort_t* wc   = Qh;                            // overlay (Q dead post-scores)
    (void)Kh; (void)Vth;

    for (int h = 0; h < 3; ++h) {
      // fused 3-source W conversion: one dispatch instead of three
      cvt3_f32_bf16<<<dim3(4096, 3), blk, 0, stream>>>(
          Wq + h * SL, Wk + h * SL, Wv + h * SL, Wcat, SL);

      // fused QKV projection: M=8192, N=6144; QS slab = 16777216 elements
      gemm256<5><<<dim3(24, 32), blk512, 0, stream>>>(
          xb, Wcat, Qh, nullptr, 2048, 2048, 2048, 2048,
          0L, 0L, 16777216L, 1.0f);
      // scores -> bf16, batched z=b
      gemm256<1><<<dim3(8, 8, 4), blk512, 0, stream>>>(
          Qh, Qh + 16777216L, Sb, nullptr, 2048, 2048, 2048, 2048,
          SL, SL, SL, scale);
      softmax_cols_v2<<<dim3(32, 4), blk, 0, stream>>>(Sb, wc);
      // meanbP[b] (+)= (1/3) * wc[b] @ Vth[b]^T   (bf16 accumulate)
      if (h == 0)
        gemm256<1><<<dim3(8, 8, 4), blk512, 0, stream>>>(
            wc, Qh + 33554432L, meanbP, nullptr, 2048, 2048, 2048, 2048,
            SL, SL, SL, 1.0f / 3.0f);
      else
        gemm256<6><<<dim3(8, 8, 4), blk512, 0, stream>>>(
            wc, Qh + 33554432L, meanbP, nullptr, 2048, 2048, 2048, 2048,
            SL, SL, SL, 1.0f / 3.0f);
    }

    // out = meanbP @ fc_w^T + fc_b
    gemm256<3><<<dim3(8, 32), blk512, 0, stream>>>(
        meanbP, fcwb, out, fcb, 2048, 2048, 2048, 2048,
        0L, 0L, 0L, 1.0f);
  } else {
    // compact: exact round-3 footprint (109,051,904 bytes; proven safe).
    // Kept byte-identical to the verified round-7 path (unknown ws bound).
    float* mean32 = out;  // fp32 head-sum accumulator in d_out
    ushort_t* Wqh  = (ushort_t*)alloc(8388608);  // [2048][2048] -+
    ushort_t* Wkh  = (ushort_t*)alloc(8388608);  //               | contiguous
    ushort_t* Wvh  = (ushort_t*)alloc(8388608);  //              -+ = [6144][2048]
    ushort_t* Qhb  = (ushort_t*)alloc(8388608);  // [2048][2048] -+
    ushort_t* Khb  = (ushort_t*)alloc(8388608);  //               | contiguous
    ushort_t* Vthb = (ushort_t*)alloc(8388608);  //              -+
    float*    S    = (float*)alloc(16777216);    // [2048][2048] fp32
    ushort_t* wchb = Qhb;                        // overlay
    (void)Wkh; (void)Wvh; (void)Khb; (void)Vthb;

    for (int h = 0; h < 3; ++h) {
      cvt_f32_bf16<<<4096, blk, 0, stream>>>(Wq + h * SL, Wqh, SL);
      cvt_f32_bf16<<<4096, blk, 0, stream>>>(Wk + h * SL, Wqh + SL, SL);
      cvt_f32_bf16<<<4096, blk, 0, stream>>>(Wv + h * SL, Wqh + 2 * SL, SL);

      for (int b = 0; b < 4; ++b) {
        const ushort_t* xbb = xb + b * SL;
        // fused QKV projection: M=2048, N=6144; QS slab = 4194304 elements
        gemm256<5><<<dim3(24, 8), blk512, 0, stream>>>(
            xbb, Wqh, Qhb, nullptr, 2048, 2048, 2048, 2048,
            0L, 0L, 4194304L, 1.0f);
        gemm256<0><<<dim3(8, 8), blk512, 0, stream>>>(
            Qhb, Qhb + SL, S, nullptr, 2048, 2048, 2048, 2048,
            0L, 0L, 0L, scale);
        softmax_cols<0><<<dim3(64, 1), blk, 0, stream>>>(S, wchb);
        if (h == 0)
          gemm256<0><<<dim3(8, 8), blk512, 0, stream>>>(
              wchb, Qhb + 2 * SL, mean32 + b * SL, nullptr, 2048,
              2048, 2048, 2048, 0L, 0L, 0L, 1.0f / 3.0f);
        else
          gemm256<4><<<dim3(8, 8), blk512, 0, stream>>>(
              wchb, Qhb + 2 * SL, mean32 + b * SL, nullptr, 2048,
              2048, 2048, 2048, 0L, 0L, 0L, 1.0f / 3.0f);
      }
    }

    // mean (in d_out) -> bf16 overlay in loop region, then FC
    ushort_t* meanb = (ushort_t*)loop0;
    cvt_f32_bf16<<<16384, blk, 0, stream>>>(mean32, meanb, 16777216L);
    gemm256<3><<<dim3(8, 32), blk512, 0, stream>>>(
        meanb, fcwb, out, fcb, 2048, 2048, 2048, 2048,
        0L, 0L, 0L, 1.0f);
  }
}